// Round 6
// baseline (766.263 us; speedup 1.0000x reference)
//
#include <hip/hip_runtime.h>
#include <math.h>

#define BLOCK_ 512
#define BPB_   8
#define NBLK_  (8192/BPB_)   // 1024 blocks

typedef __bf16 bf16x8 __attribute__((ext_vector_type(8)));
typedef float  f32x4  __attribute__((ext_vector_type(4)));
typedef unsigned short us8 __attribute__((ext_vector_type(8)));

// element strides (16B-aligned rows, <=2-way bank aliasing)
#define XS_  72    // x bf16      (144B)
#define QKS_ 136   // qk bf16     (272B)
#define VS_  72    // v bf16      (144B)
#define CS_  68    // canvas f32  (272B)
#define W1S_ 72
#define W2S_ 40
#define HGS_ 40    // H1g bf16 (overlays QK)

struct alignas(16) Smem {
    unsigned short Xb[96*XS_];    // 13824 B (rows 81..95 zero pad)
    unsigned short QK[81*QKS_];   // 22032 B (q cols 0-63, k cols 64-127; H1g overlays)
    unsigned short Vf[81*VS_];    // 11664 B (bf16)
    float          Cv[81*CS_];    // 22032 B (atomic canvas)
    unsigned short W1[32*W1S_];   //  4608 B
    unsigned short W2[64*W2S_];   //  5120 B
    float Bias[81];
    float B1v[32], LnG[32], LnB[32], B2v[64];
};  // 80,244 B -> 2 blocks/CU (LDS-capped at 4 waves/SIMD)

__device__ __forceinline__ unsigned short f2bf(float f) {
    union { float f; unsigned u; } v; v.f = f;
    unsigned r = v.u + 0x7FFFu + ((v.u >> 16) & 1u);   // RNE
    return (unsigned short)(r >> 16);
}
__device__ __forceinline__ float bf2f(unsigned short b) {
    union { float f; unsigned u; } v; v.u = ((unsigned)b) << 16;
    return v.f;
}
__device__ __forceinline__ us8 pack8(float4 a, float4 b) {
    us8 r;
    r[0]=f2bf(a.x); r[1]=f2bf(a.y); r[2]=f2bf(a.z); r[3]=f2bf(a.w);
    r[4]=f2bf(b.x); r[5]=f2bf(b.y); r[6]=f2bf(b.z); r[7]=f2bf(b.w);
    return r;
}
__device__ __forceinline__ f32x4 mfma16(us8 a, us8 b, f32x4 c) {
    return __builtin_amdgcn_mfma_f32_16x16x32_bf16(
        __builtin_bit_cast(bf16x8, a), __builtin_bit_cast(bf16x8, b), c, 0, 0, 0);
}

// LDS caps occupancy at 2 blocks/CU = 4 waves/EU. Pin the compiler's
// occupancy target to exactly that -> VGPR budget 128, no spill-to-64.
__global__ __attribute__((amdgpu_flat_work_group_size(512, 512)))
           __attribute__((amdgpu_waves_per_eu(4, 4)))
void wattn_mfma(const float* __restrict__ x, const float* __restrict__ w_qkv,
                const float* __restrict__ pe, const float* __restrict__ w1,
                const float* __restrict__ b1, const float* __restrict__ lng,
                const float* __restrict__ lnb, const float* __restrict__ w2,
                const float* __restrict__ b2, float* __restrict__ out)
{
    __shared__ Smem sm;
    const int t = threadIdx.x;
    const int wv = t >> 6, lane = t & 63;
    const int lrow = lane & 15;
    const int lk   = (lane >> 4) * 8;   // A/B frag k-offset
    const int g4   = (lane >> 4) * 4;   // D row-group

    // ---- Wqkv B-fragments -> registers (this wave's 3 n-tiles x 2 k-steps) ----
    const int ng = wv & 3, mg = wv >> 2;
    us8 bq[3][2];
    #pragma unroll
    for (int ni = 0; ni < 3; ++ni)
        #pragma unroll
        for (int k = 0; k < 2; ++k) {
            const float4* src = (const float4*)(w_qkv + ((ng*3+ni)*16 + lrow)*64 + k*32 + lk);
            bq[ni][k] = pack8(src[0], src[1]);
        }

    // ---------------- prologue: LDS weights + bias + zeros + x[0] ----------------
    for (int task = t; task < 32*8; task += BLOCK_) {
        int p = task >> 3, c8 = task & 7;
        const float4* src = (const float4*)(w1 + p*64 + c8*8);
        *(us8*)&sm.W1[p*W1S_ + c8*8] = pack8(src[0], src[1]);
    }
    for (int task = t; task < 64*4; task += BLOCK_) {
        int p = task >> 2, c8 = task & 3;
        const float4* src = (const float4*)(w2 + p*32 + c8*8);
        *(us8*)&sm.W2[p*W2S_ + c8*8] = pack8(src[0], src[1]);
    }
    if (t < 32) { sm.B1v[t]=b1[t]; sm.LnG[t]=lng[t]; sm.LnB[t]=lnb[t]; }
    if (t >= 64 && t < 128) sm.B2v[t-64] = b2[t-64];
    if (t >= 128 && t < 209) {
        int ij = t-128; int i = ij/9, j = ij%9;
        sm.Bias[ij] = pe[((j/3)-(i/3)+2)*5 + ((j%3)-(i%3)+2)];
    }
    for (int idx = t; idx < 81*CS_; idx += BLOCK_) sm.Cv[idx] = 0.f;
    for (int idx = t; idx < 15*XS_; idx += BLOCK_)
        sm.Xb[(81 + idx/XS_)*XS_ + idx%XS_] = 0;   // zero pad rows 81..95
    {
        const float* xb = x + (size_t)blockIdx.x * BPB_ * (81*64);
        for (int task = t; task < 648; task += BLOCK_) {
            int p = task >> 3, c8 = task & 7;
            const float4* src = (const float4*)(xb + p*64 + c8*8);
            *(us8*)&sm.Xb[p*XS_ + c8*8] = pack8(src[0], src[1]);
        }
    }
    __syncthreads();

    for (int bi = 0; bi < BPB_; ++bi) {
        const size_t b = (size_t)blockIdx.x * BPB_ + bi;

        // -------- issue next batch's x loads (written into Xb late in phase C) --------
        float4 pA0, pA1, pB0, pB1;
        const bool hasPF = (bi + 1 < BPB_);
        const bool hasPF2 = hasPF && (t < 136);
        if (hasPF) {
            const float4* xn = (const float4*)(x + (b+1)*(81*64));
            pA0 = xn[t*2]; pA1 = xn[t*2+1];
            if (hasPF2) { pB0 = xn[(512+t)*2]; pB1 = xn[(512+t)*2+1]; }
        }

        // -------- phase A: qkv = x @ Wqkv^T via MFMA (6m x 12n, K=64) --------
        {
            us8 af[3][2];
            #pragma unroll
            for (int mi = 0; mi < 3; ++mi)
                #pragma unroll
                for (int k = 0; k < 2; ++k)
                    af[mi][k] = *(const us8*)&sm.Xb[(mg*48 + mi*16 + lrow)*XS_ + k*32 + lk];
            #pragma unroll
            for (int ni = 0; ni < 3; ++ni) {
                const int n = ng*3 + ni;
                f32x4 acc[3];
                #pragma unroll
                for (int mi = 0; mi < 3; ++mi) {
                    acc[mi][0]=0.f; acc[mi][1]=0.f; acc[mi][2]=0.f; acc[mi][3]=0.f;
                }
                #pragma unroll
                for (int k = 0; k < 2; ++k)
                    #pragma unroll
                    for (int mi = 0; mi < 3; ++mi)
                        acc[mi] = mfma16(af[mi][k], bq[ni][k], acc[mi]);
                #pragma unroll
                for (int mi = 0; mi < 3; ++mi) {
                    const int row0 = mg*48 + mi*16 + g4;
                    if (n < 8) {
                        #pragma unroll
                        for (int r = 0; r < 4; ++r) {
                            int row = row0 + r;
                            if (row < 81) sm.QK[row*QKS_ + n*16 + lrow] = f2bf(acc[mi][r]);
                        }
                    } else {
                        #pragma unroll
                        for (int r = 0; r < 4; ++r) {
                            int row = row0 + r;
                            if (row < 81) sm.Vf[row*VS_ + (n-8)*16 + lrow] = f2bf(acc[mi][r]);
                        }
                    }
                }
            }
        }
        __syncthreads();

        // -------- phase C: 576 attention tasks (w,h,i) + scrambled scatter --------
        for (int task = t; task < 576; task += BLOCK_) {
            int w = task/36, rem = task%36, h = rem/9, i = rem%9;
            int r0 = (w>>2)*2, c0 = (w&3)*2;
            int posq = (r0 + i/3)*9 + (c0 + i%3);
            float q[16];
            {
                us8 u0 = *(const us8*)&sm.QK[posq*QKS_ + h*16];
                us8 u1 = *(const us8*)&sm.QK[posq*QKS_ + h*16 + 8];
                #pragma unroll
                for (int jj=0;jj<8;++jj){ q[jj]=bf2f(u0[jj]); q[8+jj]=bf2f(u1[jj]); }
            }
            float l[9]; float mx = -1e30f;
            #pragma unroll
            for (int j = 0; j < 9; ++j) {
                int posk = (r0 + j/3)*9 + (c0 + j%3);
                us8 u0 = *(const us8*)&sm.QK[posk*QKS_ + 64 + h*16];
                us8 u1 = *(const us8*)&sm.QK[posk*QKS_ + 64 + h*16 + 8];
                float s = 0.f;
                #pragma unroll
                for (int jj=0;jj<8;++jj) s += q[jj]*bf2f(u0[jj]) + q[8+jj]*bf2f(u1[jj]);
                l[j] = s*0.25f + sm.Bias[i*9+j];
                mx = fmaxf(mx, l[j]);
            }
            float ssum = 0.f;
            #pragma unroll
            for (int j=0;j<9;++j){ l[j]=__expf(l[j]-mx); ssum+=l[j]; }
            float inv = 1.f/ssum;
            float o[16];
            #pragma unroll
            for (int d=0; d<16; ++d) o[d]=0.f;
            #pragma unroll
            for (int j = 0; j < 9; ++j) {
                float a = l[j]*inv;
                int posv = (r0 + j/3)*9 + (c0 + j%3);
                us8 v0 = *(const us8*)&sm.Vf[posv*VS_ + h*16];
                us8 v1 = *(const us8*)&sm.Vf[posv*VS_ + h*16 + 8];
                #pragma unroll
                for (int jj=0;jj<8;++jj) {
                    o[jj]   += a * bf2f(v0[jj]);
                    o[8+jj] += a * bf2f(v1[jj]);
                }
            }
            int base576 = i*64 + h*16;
            #pragma unroll
            for (int d=0; d<16; ++d) {
                int idx = base576 + d;
                int c = idx/9, r = idx - 9*c;
                int row = (r0 + r/3)*9 + (c0 + r%3);
                atomicAdd(&sm.Cv[row*CS_ + c], o[d]);
            }
        }
        // write prefetched x (single buffer: phase A done, barrier passed)
        if (hasPF) {
            int p = t >> 3, c8 = t & 7;
            *(us8*)&sm.Xb[p*XS_ + c8*8] = pack8(pA0, pA1);
            if (hasPF2) {
                int task = 512 + t; p = task >> 3; c8 = task & 7;
                *(us8*)&sm.Xb[p*XS_ + c8*8] = pack8(pB0, pB1);
            }
        }
        __syncthreads();

        // -------- phase G: MLP1 MFMA + in-reg LN + gelu --------
        if (wv < 6) {
            const int m = wv;
            const int arow = m*16 + lrow;
            us8 aF[2];
            #pragma unroll
            for (int k = 0; k < 2; ++k) {
                #pragma unroll
                for (int e=0;e<8;++e) aF[k][e] = 0;
                if (arow < 81) {
                    const float* cp = &sm.Cv[arow*CS_ + k*32 + lk];
                    aF[k] = pack8(*(const float4*)cp, *(const float4*)(cp+4));
                }
            }
            f32x4 a0, a1;
            a0[0]=0.f; a0[1]=0.f; a0[2]=0.f; a0[3]=0.f;
            a1[0]=0.f; a1[1]=0.f; a1[2]=0.f; a1[3]=0.f;
            #pragma unroll
            for (int k = 0; k < 2; ++k) {
                us8 b0  = *(const us8*)&sm.W1[lrow*W1S_ + k*32 + lk];
                us8 b1f = *(const us8*)&sm.W1[(16+lrow)*W1S_ + k*32 + lk];
                a0 = mfma16(aF[k], b0, a0);
                a1 = mfma16(aF[k], b1f, a1);
            }
            float bb0 = sm.B1v[lrow], bb1 = sm.B1v[16+lrow];
            float gg0 = sm.LnG[lrow], gg1 = sm.LnG[16+lrow];
            float ee0 = sm.LnB[lrow], ee1 = sm.LnB[16+lrow];
            float v0[4], v1[4], srow[4], qrow[4];
            #pragma unroll
            for (int r=0;r<4;++r) {
                v0[r] = a0[r] + bb0; v1[r] = a1[r] + bb1;
                srow[r] = v0[r] + v1[r];
                qrow[r] = v0[r]*v0[r] + v1[r]*v1[r];
            }
            #pragma unroll
            for (int mask = 1; mask <= 8; mask <<= 1)
                #pragma unroll
                for (int r=0;r<4;++r) {
                    srow[r] += __shfl_xor(srow[r], mask);
                    qrow[r] += __shfl_xor(qrow[r], mask);
                }
            unsigned short* H1g = sm.QK;   // overlays dead QK
            #pragma unroll
            for (int r=0;r<4;++r) {
                int row = m*16 + g4 + r;
                if (row < 81) {
                    float mean = srow[r]*(1.f/32.f);
                    float var  = qrow[r]*(1.f/32.f) - mean*mean;
                    float rs   = rsqrtf(var + 1e-5f);
                    float xn0 = (v0[r]-mean)*rs*gg0 + ee0;
                    float xn1 = (v1[r]-mean)*rs*gg1 + ee1;
                    float ge0 = 0.5f*xn0*(1.f + erff(xn0*0.70710678118654752f));
                    float ge1 = 0.5f*xn1*(1.f + erff(xn1*0.70710678118654752f));
                    H1g[row*HGS_ + lrow]      = f2bf(ge0);
                    H1g[row*HGS_ + 16 + lrow] = f2bf(ge1);
                }
            }
        }
        __syncthreads();

        // -------- phase J: MLP2 MFMA -> global; re-zero canvas --------
        {
            const unsigned short* H1g = sm.QK;
            #pragma unroll
            for (int ti = 0; ti < 3; ++ti) {
                int ft = wv*3 + ti;
                int m = ft >> 2, n = ft & 3;
                int arow = m*16 + lrow;
                us8 aH;
                #pragma unroll
                for (int e=0;e<8;++e) aH[e] = 0;
                if (arow < 81) aH = *(const us8*)&H1g[arow*HGS_ + lk];
                us8 bW = *(const us8*)&sm.W2[(n*16+lrow)*W2S_ + lk];
                f32x4 zz;
                zz[0]=0.f; zz[1]=0.f; zz[2]=0.f; zz[3]=0.f;
                f32x4 acc = mfma16(aH, bW, zz);
                float bb = sm.B2v[n*16+lrow];
                int row0 = m*16 + g4;
                #pragma unroll
                for (int r=0;r<4;++r) {
                    int row = row0 + r;
                    if (row < 81)
                        out[(b*81 + (size_t)row)*64 + n*16 + lrow] = acc[r] + bb;
                }
            }
        }
        for (int idx = t; idx < 81*CS_; idx += BLOCK_) sm.Cv[idx] = 0.f;
        __syncthreads();
    }
}

extern "C" void kernel_launch(void* const* d_in, const int* in_sizes, int n_in,
                              void* d_out, int out_size, void* d_ws, size_t ws_size,
                              hipStream_t stream) {
    const float* x     = (const float*)d_in[0];
    const float* w_qkv = (const float*)d_in[1];
    const float* pe    = (const float*)d_in[2];
    const float* w1    = (const float*)d_in[3];
    const float* b1    = (const float*)d_in[4];
    const float* lng   = (const float*)d_in[5];
    const float* lnb   = (const float*)d_in[6];
    const float* w2    = (const float*)d_in[7];
    const float* b2    = (const float*)d_in[8];
    float* outp = (float*)d_out;

    wattn_mfma<<<dim3(NBLK_), dim3(BLOCK_), 0, stream>>>(
        x, w_qkv, pe, w1, b1, lng, lnb, w2, b2, outp);
}

// Round 7
// 672.434 us; speedup vs baseline: 1.1395x; 1.1395x over previous
//
#include <hip/hip_runtime.h>
#include <math.h>

#define BLOCK_ 512
#define BPB_   8
#define NBLK_  (8192/BPB_)   // 1024 blocks

typedef __bf16 bf16x8 __attribute__((ext_vector_type(8)));
typedef float  f32x4  __attribute__((ext_vector_type(4)));
typedef unsigned short us8 __attribute__((ext_vector_type(8)));

// element strides (16B-aligned rows, <=2-way bank aliasing)
#define XS_  72    // x bf16      (144B)
#define QKS_ 136   // qk bf16     (272B)
#define VS_  72    // v bf16      (144B)
#define CS_  68    // canvas f32  (272B)
#define W1S_ 72
#define W2S_ 40
#define HGS_ 40    // H1g bf16 (overlays QK)

struct alignas(16) Smem {
    unsigned short Xb[96*XS_];    // 13824 B (rows 81..95 zero pad)
    unsigned short QK[81*QKS_];   // 22032 B (q cols 0-63, k cols 64-127; H1g overlays)
    unsigned short Vf[81*VS_];    // 11664 B (bf16)
    float          Cv[81*CS_];    // 22032 B (atomic canvas)
    unsigned short W1[32*W1S_];   //  4608 B
    unsigned short W2[64*W2S_];   //  5120 B
    float Bias[81];
    float B1v[32], LnG[32], LnB[32], B2v[64];
};  // 80,244 B -> 2 blocks/CU (LDS-capped at 4 waves/SIMD)

__device__ __forceinline__ unsigned short f2bf(float f) {
    union { float f; unsigned u; } v; v.f = f;
    unsigned r = v.u + 0x7FFFu + ((v.u >> 16) & 1u);   // RNE
    return (unsigned short)(r >> 16);
}
__device__ __forceinline__ float bf2f(unsigned short b) {
    union { float f; unsigned u; } v; v.u = ((unsigned)b) << 16;
    return v.f;
}
__device__ __forceinline__ us8 pack8(float4 a, float4 b) {
    us8 r;
    r[0]=f2bf(a.x); r[1]=f2bf(a.y); r[2]=f2bf(a.z); r[3]=f2bf(a.w);
    r[4]=f2bf(b.x); r[5]=f2bf(b.y); r[6]=f2bf(b.z); r[7]=f2bf(b.w);
    return r;
}
__device__ __forceinline__ f32x4 mfma16(us8 a, us8 b, f32x4 c) {
    return __builtin_amdgcn_mfma_f32_16x16x32_bf16(
        __builtin_bit_cast(bf16x8, a), __builtin_bit_cast(bf16x8, b), c, 0, 0, 0);
}

// NOTE: __launch_bounds__ 2nd arg behaves like CUDA (min BLOCKS/CU):
//   (512,4) => 32 waves/CU target => VGPR budget 64 => spills (rounds 5/6:
//   WRITE_SIZE +144MB scratch). (512,2) => 16 waves/CU => budget 128, no
//   spill (round 2: 88 VGPR, WRITE == out exactly). LDS caps us at
//   2 blocks/CU anyway, so 2 is the right value here.
__global__ __launch_bounds__(BLOCK_, 2)
void wattn_mfma(const float* __restrict__ x, const float* __restrict__ w_qkv,
                const float* __restrict__ pe, const float* __restrict__ w1,
                const float* __restrict__ b1, const float* __restrict__ lng,
                const float* __restrict__ lnb, const float* __restrict__ w2,
                const float* __restrict__ b2, float* __restrict__ out)
{
    __shared__ Smem sm;
    const int t = threadIdx.x;
    const int wv = t >> 6, lane = t & 63;
    const int lrow = lane & 15;
    const int lk   = (lane >> 4) * 8;   // A/B frag k-offset
    const int g4   = (lane >> 4) * 4;   // D row-group

    // ---- Wqkv B-fragments -> registers (this wave's 3 n-tiles x 2 k-steps) ----
    const int ng = wv & 3, mg = wv >> 2;
    us8 bq[3][2];
    #pragma unroll
    for (int ni = 0; ni < 3; ++ni)
        #pragma unroll
        for (int k = 0; k < 2; ++k) {
            const float4* src = (const float4*)(w_qkv + ((ng*3+ni)*16 + lrow)*64 + k*32 + lk);
            bq[ni][k] = pack8(src[0], src[1]);
        }

    // ---------------- prologue: LDS weights + bias + zeros + x[0] ----------------
    for (int task = t; task < 32*8; task += BLOCK_) {
        int p = task >> 3, c8 = task & 7;
        const float4* src = (const float4*)(w1 + p*64 + c8*8);
        *(us8*)&sm.W1[p*W1S_ + c8*8] = pack8(src[0], src[1]);
    }
    for (int task = t; task < 64*4; task += BLOCK_) {
        int p = task >> 2, c8 = task & 3;
        const float4* src = (const float4*)(w2 + p*32 + c8*8);
        *(us8*)&sm.W2[p*W2S_ + c8*8] = pack8(src[0], src[1]);
    }
    if (t < 32) { sm.B1v[t]=b1[t]; sm.LnG[t]=lng[t]; sm.LnB[t]=lnb[t]; }
    if (t >= 64 && t < 128) sm.B2v[t-64] = b2[t-64];
    if (t >= 128 && t < 209) {
        int ij = t-128; int i = ij/9, j = ij%9;
        sm.Bias[ij] = pe[((j/3)-(i/3)+2)*5 + ((j%3)-(i%3)+2)];
    }
    for (int idx = t; idx < 81*CS_; idx += BLOCK_) sm.Cv[idx] = 0.f;
    for (int idx = t; idx < 15*XS_; idx += BLOCK_)
        sm.Xb[(81 + idx/XS_)*XS_ + idx%XS_] = 0;   // zero pad rows 81..95
    {
        const float* xb = x + (size_t)blockIdx.x * BPB_ * (81*64);
        for (int task = t; task < 648; task += BLOCK_) {
            int p = task >> 3, c8 = task & 7;
            const float4* src = (const float4*)(xb + p*64 + c8*8);
            *(us8*)&sm.Xb[p*XS_ + c8*8] = pack8(src[0], src[1]);
        }
    }
    __syncthreads();

    for (int bi = 0; bi < BPB_; ++bi) {
        const size_t b = (size_t)blockIdx.x * BPB_ + bi;

        // -------- issue next batch's x loads (written into Xb late in phase C) --------
        float4 pA0, pA1, pB0, pB1;
        const bool hasPF = (bi + 1 < BPB_);
        const bool hasPF2 = hasPF && (t < 136);
        if (hasPF) {
            const float4* xn = (const float4*)(x + (b+1)*(81*64));
            pA0 = xn[t*2]; pA1 = xn[t*2+1];
            if (hasPF2) { pB0 = xn[(512+t)*2]; pB1 = xn[(512+t)*2+1]; }
        }

        // -------- phase A: qkv = x @ Wqkv^T via MFMA (6m x 12n, K=64) --------
        {
            us8 af[3][2];
            #pragma unroll
            for (int mi = 0; mi < 3; ++mi)
                #pragma unroll
                for (int k = 0; k < 2; ++k)
                    af[mi][k] = *(const us8*)&sm.Xb[(mg*48 + mi*16 + lrow)*XS_ + k*32 + lk];
            #pragma unroll
            for (int ni = 0; ni < 3; ++ni) {
                const int n = ng*3 + ni;
                f32x4 acc[3];
                #pragma unroll
                for (int mi = 0; mi < 3; ++mi) {
                    acc[mi][0]=0.f; acc[mi][1]=0.f; acc[mi][2]=0.f; acc[mi][3]=0.f;
                }
                #pragma unroll
                for (int k = 0; k < 2; ++k)
                    #pragma unroll
                    for (int mi = 0; mi < 3; ++mi)
                        acc[mi] = mfma16(af[mi][k], bq[ni][k], acc[mi]);
                #pragma unroll
                for (int mi = 0; mi < 3; ++mi) {
                    const int row0 = mg*48 + mi*16 + g4;
                    if (n < 8) {
                        #pragma unroll
                        for (int r = 0; r < 4; ++r) {
                            int row = row0 + r;
                            if (row < 81) sm.QK[row*QKS_ + n*16 + lrow] = f2bf(acc[mi][r]);
                        }
                    } else {
                        #pragma unroll
                        for (int r = 0; r < 4; ++r) {
                            int row = row0 + r;
                            if (row < 81) sm.Vf[row*VS_ + (n-8)*16 + lrow] = f2bf(acc[mi][r]);
                        }
                    }
                }
            }
        }
        __syncthreads();

        // -------- phase C: 576 attention tasks (w,h,i) + scrambled scatter --------
        for (int task = t; task < 576; task += BLOCK_) {
            int w = task/36, rem = task%36, h = rem/9, i = rem%9;
            int r0 = (w>>2)*2, c0 = (w&3)*2;
            int posq = (r0 + i/3)*9 + (c0 + i%3);
            float q[16];
            {
                us8 u0 = *(const us8*)&sm.QK[posq*QKS_ + h*16];
                us8 u1 = *(const us8*)&sm.QK[posq*QKS_ + h*16 + 8];
                #pragma unroll
                for (int jj=0;jj<8;++jj){ q[jj]=bf2f(u0[jj]); q[8+jj]=bf2f(u1[jj]); }
            }
            float l[9]; float mx = -1e30f;
            #pragma unroll
            for (int j = 0; j < 9; ++j) {
                int posk = (r0 + j/3)*9 + (c0 + j%3);
                us8 u0 = *(const us8*)&sm.QK[posk*QKS_ + 64 + h*16];
                us8 u1 = *(const us8*)&sm.QK[posk*QKS_ + 64 + h*16 + 8];
                float s = 0.f;
                #pragma unroll
                for (int jj=0;jj<8;++jj) s += q[jj]*bf2f(u0[jj]) + q[8+jj]*bf2f(u1[jj]);
                l[j] = s*0.25f + sm.Bias[i*9+j];
                mx = fmaxf(mx, l[j]);
            }
            float ssum = 0.f;
            #pragma unroll
            for (int j=0;j<9;++j){ l[j]=__expf(l[j]-mx); ssum+=l[j]; }
            float inv = 1.f/ssum;
            float o[16];
            #pragma unroll
            for (int d=0; d<16; ++d) o[d]=0.f;
            #pragma unroll
            for (int j = 0; j < 9; ++j) {
                float a = l[j]*inv;
                int posv = (r0 + j/3)*9 + (c0 + j%3);
                us8 v0 = *(const us8*)&sm.Vf[posv*VS_ + h*16];
                us8 v1 = *(const us8*)&sm.Vf[posv*VS_ + h*16 + 8];
                #pragma unroll
                for (int jj=0;jj<8;++jj) {
                    o[jj]   += a * bf2f(v0[jj]);
                    o[8+jj] += a * bf2f(v1[jj]);
                }
            }
            int base576 = i*64 + h*16;
            #pragma unroll
            for (int d=0; d<16; ++d) {
                int idx = base576 + d;
                int c = idx/9, r = idx - 9*c;
                int row = (r0 + r/3)*9 + (c0 + r%3);
                atomicAdd(&sm.Cv[row*CS_ + c], o[d]);
            }
        }
        // write prefetched x (single buffer: phase A done, barrier passed)
        if (hasPF) {
            int p = t >> 3, c8 = t & 7;
            *(us8*)&sm.Xb[p*XS_ + c8*8] = pack8(pA0, pA1);
            if (hasPF2) {
                int task = 512 + t; p = task >> 3; c8 = task & 7;
                *(us8*)&sm.Xb[p*XS_ + c8*8] = pack8(pB0, pB1);
            }
        }
        __syncthreads();

        // -------- phase G: MLP1 MFMA + in-reg LN + gelu --------
        if (wv < 6) {
            const int m = wv;
            const int arow = m*16 + lrow;
            us8 aF[2];
            #pragma unroll
            for (int k = 0; k < 2; ++k) {
                #pragma unroll
                for (int e=0;e<8;++e) aF[k][e] = 0;
                if (arow < 81) {
                    const float* cp = &sm.Cv[arow*CS_ + k*32 + lk];
                    aF[k] = pack8(*(const float4*)cp, *(const float4*)(cp+4));
                }
            }
            f32x4 a0, a1;
            a0[0]=0.f; a0[1]=0.f; a0[2]=0.f; a0[3]=0.f;
            a1[0]=0.f; a1[1]=0.f; a1[2]=0.f; a1[3]=0.f;
            #pragma unroll
            for (int k = 0; k < 2; ++k) {
                us8 b0  = *(const us8*)&sm.W1[lrow*W1S_ + k*32 + lk];
                us8 b1f = *(const us8*)&sm.W1[(16+lrow)*W1S_ + k*32 + lk];
                a0 = mfma16(aF[k], b0, a0);
                a1 = mfma16(aF[k], b1f, a1);
            }
            float bb0 = sm.B1v[lrow], bb1 = sm.B1v[16+lrow];
            float gg0 = sm.LnG[lrow], gg1 = sm.LnG[16+lrow];
            float ee0 = sm.LnB[lrow], ee1 = sm.LnB[16+lrow];
            float v0[4], v1[4], srow[4], qrow[4];
            #pragma unroll
            for (int r=0;r<4;++r) {
                v0[r] = a0[r] + bb0; v1[r] = a1[r] + bb1;
                srow[r] = v0[r] + v1[r];
                qrow[r] = v0[r]*v0[r] + v1[r]*v1[r];
            }
            #pragma unroll
            for (int mask = 1; mask <= 8; mask <<= 1)
                #pragma unroll
                for (int r=0;r<4;++r) {
                    srow[r] += __shfl_xor(srow[r], mask);
                    qrow[r] += __shfl_xor(qrow[r], mask);
                }
            unsigned short* H1g = sm.QK;   // overlays dead QK
            #pragma unroll
            for (int r=0;r<4;++r) {
                int row = m*16 + g4 + r;
                if (row < 81) {
                    float mean = srow[r]*(1.f/32.f);
                    float var  = qrow[r]*(1.f/32.f) - mean*mean;
                    float rs   = rsqrtf(var + 1e-5f);
                    float xn0 = (v0[r]-mean)*rs*gg0 + ee0;
                    float xn1 = (v1[r]-mean)*rs*gg1 + ee1;
                    float ge0 = 0.5f*xn0*(1.f + erff(xn0*0.70710678118654752f));
                    float ge1 = 0.5f*xn1*(1.f + erff(xn1*0.70710678118654752f));
                    H1g[row*HGS_ + lrow]      = f2bf(ge0);
                    H1g[row*HGS_ + 16 + lrow] = f2bf(ge1);
                }
            }
        }
        __syncthreads();

        // -------- phase J: MLP2 MFMA -> global; re-zero canvas --------
        {
            const unsigned short* H1g = sm.QK;
            #pragma unroll
            for (int ti = 0; ti < 3; ++ti) {
                int ft = wv*3 + ti;
                int m = ft >> 2, n = ft & 3;
                int arow = m*16 + lrow;
                us8 aH;
                #pragma unroll
                for (int e=0;e<8;++e) aH[e] = 0;
                if (arow < 81) aH = *(const us8*)&H1g[arow*HGS_ + lk];
                us8 bW = *(const us8*)&sm.W2[(n*16+lrow)*W2S_ + lk];
                f32x4 zz;
                zz[0]=0.f; zz[1]=0.f; zz[2]=0.f; zz[3]=0.f;
                f32x4 acc = mfma16(aH, bW, zz);
                float bb = sm.B2v[n*16+lrow];
                int row0 = m*16 + g4;
                #pragma unroll
                for (int r=0;r<4;++r) {
                    int row = row0 + r;
                    if (row < 81)
                        out[(b*81 + (size_t)row)*64 + n*16 + lrow] = acc[r] + bb;
                }
            }
        }
        for (int idx = t; idx < 81*CS_; idx += BLOCK_) sm.Cv[idx] = 0.f;
        __syncthreads();
    }
}

extern "C" void kernel_launch(void* const* d_in, const int* in_sizes, int n_in,
                              void* d_out, int out_size, void* d_ws, size_t ws_size,
                              hipStream_t stream) {
    const float* x     = (const float*)d_in[0];
    const float* w_qkv = (const float*)d_in[1];
    const float* pe    = (const float*)d_in[2];
    const float* w1    = (const float*)d_in[3];
    const float* b1    = (const float*)d_in[4];
    const float* lng   = (const float*)d_in[5];
    const float* lnb   = (const float*)d_in[6];
    const float* w2    = (const float*)d_in[7];
    const float* b2    = (const float*)d_in[8];
    float* outp = (float*)d_out;

    wattn_mfma<<<dim3(NBLK_), dim3(BLOCK_), 0, stream>>>(
        x, w_qkv, pe, w1, b1, lng, lnb, w2, b2, outp);
}